// Round 1
// 452.109 us; speedup vs baseline: 1.0406x; 1.0406x over previous
//
#include <hip/hip_runtime.h>
#include <math.h>

// Problem constants (from reference setup_inputs)
constexpr int N  = 8;
constexpr int C  = 32;
constexpr int H  = 256;
constexpr int W  = 256;
constexpr int HU = 512;   // upsampled H
constexpr int WU = 512;   // upsampled W

// Output tile per 256-thread block: 64 wide x 4 high.
// Wave = one 64-wide output row strip -> each vector-load instruction's 64
// lanes touch ONE input row (span ~ 64*|th0| floats), not 4 rows like the
// old 16x4 wave mapping. This cuts per-instruction cache-line transactions
// ~4x, which is the measured bottleneck (latency/transaction-bound: 19% HBM,
// 15% VALU, minimal traffic).
constexpr int TX = 64;
constexpr int TY = 4;

// Under-aligned float4: one global_load_dwordx4 per 3-tap stencil row
// (gfx950 tolerates dword-aligned dwordx4; 4th lane is discarded).
typedef float f4 __attribute__((ext_vector_type(4)));
typedef f4 f4u __attribute__((aligned(4)));

// Per-axis decomposition of (grid_sample bilinear) o (upsample2x bilinear):
// a continuous coordinate into the virtual upsampled axis collapses to a
// 3-consecutive-texel window of the ORIGINAL axis with 3 merged weights.
struct Axis {
    int   base;          // window base in original axis, in [0, n_in-3]
    float w0, w1, w2;    // weights for base, base+1, base+2
};

__device__ __forceinline__ Axis make_axis(float coord, int n_in, int n_up) {
    float c0f = floorf(coord);
    float t   = coord - c0f;         // grid_sample frac weight
    int   u0  = (int)c0f;            // upsampled-axis corner a

    float w3_0 = 0.f, w3_1 = 0.f, w3_2 = 0.f;
    int rb = 0;

    #pragma unroll
    for (int k = 0; k < 2; ++k) {
        int   yu    = u0 + k;
        float Wc    = (k == 0) ? (1.0f - t) : t;      // grid_sample corner weight
        bool  valid = (yu >= 0) && (yu < n_up);       // zero-padding mask

        // upsample2x source: s = (yu+0.5)/2 - 0.5, clamped >= 0
        float s  = fmaxf(0.5f * (float)yu - 0.25f, 0.0f);
        int   r0 = (int)s;                            // floor (s >= 0)
        r0 = min(r0, n_in - 1);                       // keep in-bounds for wild yu
        float wu = s - (float)r0;
        int   r1 = min(r0 + 1, n_in - 1);

        float w0 = valid ? Wc * (1.0f - wu) : 0.0f;
        float w1 = valid ? Wc * wu          : 0.0f;

        if (k == 0) rb = min(r0, n_in - 3);           // window base from corner a

        int s0 = min(max(r0 - rb, 0), 2);
        int s1 = min(max(r1 - rb, 0), 2);
        // branchless scatter into 3 slots (keeps everything in registers)
        w3_0 += (s0 == 0) ? w0 : 0.0f;
        w3_1 += (s0 == 1) ? w0 : 0.0f;
        w3_2 += (s0 == 2) ? w0 : 0.0f;
        w3_0 += (s1 == 0) ? w1 : 0.0f;
        w3_1 += (s1 == 1) ? w1 : 0.0f;
        w3_2 += (s1 == 2) ? w1 : 0.0f;
    }

    Axis ax;
    ax.base = rb;
    ax.w0 = w3_0; ax.w1 = w3_1; ax.w2 = w3_2;
    return ax;
}

__global__ __launch_bounds__(256)
void fused_up_affine_sample(const float* __restrict__ x,
                            const float* __restrict__ theta,
                            float* __restrict__ out) {
    int lane = threadIdx.x & 63;          // position within wave
    int wv   = threadIdx.x >> 6;          // wave id within block
    int wo = blockIdx.x * TX + lane;      // output col (wave = 64x1 strip)
    int ho = blockIdx.y * TY + wv;        // output row
    int n  = blockIdx.z;                  // block-uniform -> SGPR theta

    // affine grid (reference: xs=(2w+1)/W-1, ys=(2h+1)/H-1)
    float gx = (2.0f * (float)wo + 1.0f) * (1.0f / (float)WU) - 1.0f;
    float gy = (2.0f * (float)ho + 1.0f) * (1.0f / (float)HU) - 1.0f;

    const float* th = theta + n * 6;
    float ox = th[0] * gx + th[1] * gy + th[2];
    float oy = th[3] * gx + th[4] * gy + th[5];

    // grid_sample continuous coords into the (virtual) upsampled image
    float ix = ((ox + 1.0f) * (float)WU - 1.0f) * 0.5f;
    float iy = ((oy + 1.0f) * (float)HU - 1.0f) * 0.5f;

    Axis axx = make_axis(ix, W, WU);
    Axis axy = make_axis(iy, H, HU);

    // uniform bases (SGPR) + per-lane 32-bit offsets -> saddr-form loads,
    // scalar per-channel pointer increments
    const float* xb = x   + (size_t)n * (C * H * W);
    float*       ob = out + (size_t)n * (C * HU * WU);
    int loff = axy.base * W + axx.base;   // per-lane load offset (elements)
    int soff = ho * WU + wo;              // per-lane store offset

    float hw0 = axx.w0, hw1 = axx.w1, hw2 = axx.w2;
    float vw0 = axy.w0, vw1 = axy.w1, vw2 = axy.w2;

    // Channels 0..C-2: dwordx4 row loads. The extra (4th) element is never
    // used; its address stays inside the tensor for all c < C-1.
    #pragma unroll 4
    for (int c = 0; c < C - 1; ++c) {
        const float* p = xb + c * (H * W) + loff;
        f4 a = *(const f4u*)(p);
        f4 b = *(const f4u*)(p + W);
        f4 d = *(const f4u*)(p + 2 * W);
        float r0 = a.x * hw0 + a.y * hw1 + a.z * hw2;
        float r1 = b.x * hw0 + b.y * hw1 + b.z * hw2;
        float r2 = d.x * hw0 + d.y * hw1 + d.z * hw2;
        ob[c * (HU * WU) + soff] = vw0 * r0 + vw1 * r1 + vw2 * r2;
    }

    // Last channel: scalar 3-tap loads — avoids the one case where the
    // dwordx4 over-read could touch 4B past the end of the 64MB input
    // (n=N-1, c=C-1, bottom-right window).
    {
        const float* p = xb + (C - 1) * (H * W) + loff;
        float r0 = p[0        ] * hw0 + p[1        ] * hw1 + p[2        ] * hw2;
        float r1 = p[W        ] * hw0 + p[W + 1    ] * hw1 + p[W + 2    ] * hw2;
        float r2 = p[2 * W    ] * hw0 + p[2 * W + 1] * hw1 + p[2 * W + 2] * hw2;
        ob[(C - 1) * (HU * WU) + soff] = vw0 * r0 + vw1 * r1 + vw2 * r2;
    }
}

extern "C" void kernel_launch(void* const* d_in, const int* in_sizes, int n_in,
                              void* d_out, int out_size, void* d_ws, size_t ws_size,
                              hipStream_t stream) {
    const float* x     = (const float*)d_in[0];
    const float* theta = (const float*)d_in[1];
    float*       out   = (float*)d_out;

    dim3 grid(WU / TX, HU / TY, N);   // 8 x 128 x 8 = 8192 blocks
    fused_up_affine_sample<<<grid, 256, 0, stream>>>(x, theta, out);
}